// Round 5
// baseline (134.695 us; speedup 1.0000x reference)
//
#include <hip/hip_runtime.h>
#include <math.h>

#define PH 7
#define PW 7
#define BB 4
#define HH 64
#define WW 64
#define CC 256
#define RR 128
#define CH4 (CC / 4)                   // 64 float4 per pixel
#define BINS_PER_IMG (RR * PH * PW)    // 6272
#define NBINS (BB * BINS_PER_IMG)      // 25088
#define NBLK (NBINS / 4)               // 6272 blocks, 4 waves each
#define BLK_PER_IMG (NBLK / 8)         // 784 per xcd slot
#define REPS 4                         // PROBE: x4 work in one dispatch

typedef float f4 __attribute__((ext_vector_type(4)));

__device__ __forceinline__ f4 max4(f4 a, f4 b) {
    f4 r;
    r.x = fmaxf(a.x, b.x); r.y = fmaxf(a.y, b.y);
    r.z = fmaxf(a.z, b.z); r.w = fmaxf(a.w, b.w);
    return r;
}

// ===== R5: re-run of the R4 MEASUREMENT PROBE (v1 structure, REPS=4) =====
// R4 failed with a container infra error (no result). Identical probe, but
// the opaque zero is now an empty asm opacity fence ("+s" on a 0-init int;
// emits NO instruction) instead of an explicit s_mov SGPR def -- removes the
// only unusual construct in case compile/graph-capture was the failure.
//
// Purpose (unchanged): the ROI kernel has never appeared in the top-5
// counter rows; dur_us has sat at 88.5 ~= 2 x 44.2us poison-fill across
// v1/v2/v4 while structural rewrites were neutral. Repeating the identical
// per-wave workload 4x (idempotent under max, single store, per-rep opaque
// base so loads can't be CSE'd) makes the kernel's marginal time directly
// readable:  k = (dur_us - 88.5) / 3,  and if 4k > ~44us the kernel enters
// the top-5 rows -> direct FETCH_SIZE / VALUBusy / OccupancyPercent
// evidence for which pipe eats the time.
__global__ __launch_bounds__(256) void ROIPoolingLayer_62079457296467_kernel(
    const float* __restrict__ fm, const float* __restrict__ rois,
    float* __restrict__ out)
{
    const int wave = threadIdx.x >> 6;
    const int lane = threadIdx.x & 63;

    // ---- XCD swizzle: 6272 blocks = 8 xcds x 784; image b -> xcds {2b,2b+1}
    const int bid   = blockIdx.x;
    const int xcd   = bid & 7;
    const int slot  = bid >> 3;                     // 0..783
    const int b     = xcd >> 1;                     // image 0..3
    const int blkin = (xcd & 1) * BLK_PER_IMG + slot;  // 0..1567 in image
    const int local = blkin * 4 + wave;             // 0..6271 = r*49 + bin
    const int r     = local / (PH * PW);
    const int bin   = local - r * (PH * PW);
    const int ph    = bin / PW;
    const int pw    = bin - ph * PW;
    const int br    = b * RR + r;

    // ---- ROI decode (reference fp32 semantics, truncating casts) ----
    const f4 roi = ((const f4*)rois)[br];
    const int h0 = (int)floorf((float)HH * roi.x);
    const int w0 = (int)floorf((float)WW * roi.y);
    const int h1 = (int)floorf((float)HH * roi.z);
    const int w1 = (int)floorf((float)WW * roi.w);
    const int rh = h1 - h0;
    const int rw = w1 - w0;
    const int hstep = max(rh / PH, 1);
    const int wstep = max(rw / PW, 1);

    // Bin window [hs,he) x [ws,we); last bin extends to region end.
    int hs = h0 + ph * hstep;
    int he = (ph == PH - 1) ? (h0 + rh) : (hs + hstep);
    he = min(he, h0 + rh);  he = min(he, HH);
    int ws = w0 + pw * wstep;
    int we = (pw == PW - 1) ? (w0 + rw) : (ws + wstep);
    we = min(we, w0 + rw);  we = min(we, WW);

    const int hbin = he - hs;
    const int wbin = we - ws;
    const int npix = hbin * wbin;

    const f4* __restrict__ fmb =
        (const f4*)fm + ((size_t)b * HH + hs) * (WW * CH4) + (size_t)ws * CH4 + lane;

    f4 acc = (f4){-INFINITY, -INFINITY, -INFINITY, -INFINITY};

    if (npix > 0) {
        // magic divide by wbin: q = (p*m)>>16 == p/wbin for p*e < 2^16
        const unsigned m = (65536u + (unsigned)wbin - 1) / (unsigned)wbin;

        for (int rep = 0; rep < REPS; ++rep) {
            // opacity fence: z==0 at runtime, but not provably 0 to the
            // optimizer -> per-rep addresses not CSE-able, all reps stay
            // live through the final store (guide rule #17). No instruction
            // is emitted for the empty asm itself.
            int z = 0;
            asm volatile("" : "+s"(z));
            const f4* __restrict__ bp = fmb + z;

            for (int p = 0; p < npix; p += 8) {
                f4 v[8];
#pragma unroll
                for (int k = 0; k < 8; ++k) {
                    const int pk = min(p + k, npix - 1);        // clamp: dup ok
                    const int q  = (int)(((unsigned)pk * m) >> 16);  // row in bin
                    const int w  = pk - q * wbin;                    // col in bin
                    v[k] = bp[((size_t)q * WW + w) * CH4];
                }
#pragma unroll
                for (int k = 0; k < 8; ++k)
                    acc = max4(acc, v[k]);
            }
        }
    }

    // Output (b,r,ph,pw,C): gbin = b*6272 + local; non-temporal (never re-read).
    const size_t gbin = (size_t)b * BINS_PER_IMG + local;
    __builtin_nontemporal_store(acc, (f4*)out + gbin * CH4 + lane);
}

extern "C" void kernel_launch(void* const* d_in, const int* in_sizes, int n_in,
                              void* d_out, int out_size, void* d_ws, size_t ws_size,
                              hipStream_t stream) {
    const float* fm   = (const float*)d_in[0];
    const float* rois = (const float*)d_in[1];
    float* out        = (float*)d_out;
    ROIPoolingLayer_62079457296467_kernel<<<NBLK, 256, 0, stream>>>(fm, rois, out);
}

// Round 6
// 88.451 us; speedup vs baseline: 1.5228x; 1.5228x over previous
//
#include <hip/hip_runtime.h>
#include <math.h>

#define PH 7
#define PW 7
#define BB 4
#define HH 64
#define WW 64
#define CC 256
#define RR 128
#define CH4 (CC / 4)                   // 64 float4 per pixel
#define BINS_PER_IMG (RR * PH * PW)    // 6272
#define NBINS (BB * BINS_PER_IMG)      // 25088
#define NBLK (NBINS / 4)               // 6272 blocks, 4 waves each
#define BLK_PER_IMG (NBLK / 8)         // 784 per xcd slot

typedef float f4 __attribute__((ext_vector_type(4)));

__device__ __forceinline__ f4 max4(f4 a, f4 b) {
    f4 r;
    r.x = fmaxf(a.x, b.x); r.y = fmaxf(a.y, b.y);
    r.z = fmaxf(a.z, b.z); r.w = fmaxf(a.w, b.w);
    return r;
}

// v6: SGPR-scalarized addressing. R5 probe (REPS=4, kernel visible in top-5)
// measured the true kernel: ~19us/rep, VALUBusy 53%, HBM 6%, VGPR=28.
// Diagnosis: everything derived from threadIdx>>6 is marked divergent by the
// compiler, so all per-pixel address math (~6 ops/px) runs on the VALU in
// VGPRs -- and at VGPR=28 the 8-deep load batch (needs 32 data VGPRs) was
// serialized, killing MLP. Fix: readfirstlane the wave-uniform scalars
// (hbin/wbin/npix/base) into SGPRs -> pk/q/w/offset become SALU (separate
// pipe), loads become SGPR-base + lane*16 voffset, VALU shrinks to the 4
// v_max per pixel, freed VGPRs let 8 loads genuinely stay in flight.
// Everything else is v1's proven structure: wave per bin, lane = 4 channels
// (1KB coalesced txn), XCD swizzle image b -> xcds {2b,2b+1} (FETCH 50->12MB).
__global__ __launch_bounds__(256) void ROIPoolingLayer_62079457296467_kernel(
    const float* __restrict__ fm, const float* __restrict__ rois,
    float* __restrict__ out)
{
    const int wave = threadIdx.x >> 6;
    const int lane = threadIdx.x & 63;

    // ---- XCD swizzle: 6272 blocks = 8 xcds x 784; image b -> xcds {2b,2b+1}
    const int bid   = blockIdx.x;
    const int xcd   = bid & 7;
    const int slot  = bid >> 3;                     // 0..783
    const int b     = xcd >> 1;                     // image 0..3
    const int blkin = (xcd & 1) * BLK_PER_IMG + slot;  // 0..1567 in image
    const int local = blkin * 4 + wave;             // 0..6271 = r*49 + bin
    const int r     = local / (PH * PW);
    const int bin   = local - r * (PH * PW);
    const int ph    = bin / PW;
    const int pw    = bin - ph * PW;
    const int br    = b * RR + r;

    // ---- ROI decode (reference fp32 semantics, truncating casts) ----
    const f4 roi = ((const f4*)rois)[br];
    const int h0 = (int)floorf((float)HH * roi.x);
    const int w0 = (int)floorf((float)WW * roi.y);
    const int h1 = (int)floorf((float)HH * roi.z);
    const int w1 = (int)floorf((float)WW * roi.w);
    const int rh = h1 - h0;
    const int rw = w1 - w0;
    const int hstep = max(rh / PH, 1);
    const int wstep = max(rw / PW, 1);

    // Bin window [hs,he) x [ws,we); last bin extends to region end.
    int hs = h0 + ph * hstep;
    int he = (ph == PH - 1) ? (h0 + rh) : (hs + hstep);
    he = min(he, h0 + rh);  he = min(he, HH);
    int ws = w0 + pw * wstep;
    int we = (pw == PW - 1) ? (w0 + rw) : (ws + wstep);
    we = min(we, w0 + rw);  we = min(we, WW);

    // ---- scalarize wave-uniform values into SGPRs (divergence-analysis
    // can't see that threadIdx>>6-derived values are wave-uniform) ----
    const int s_hbin = __builtin_amdgcn_readfirstlane(he - hs);
    const int s_wbin = __builtin_amdgcn_readfirstlane(we - ws);
    const int s_base = __builtin_amdgcn_readfirstlane((b * HH + hs) * WW + ws);
    const int s_npix = s_hbin * s_wbin;             // SALU from here on

    // wave-uniform SGPR base; per-lane part is the constant lane*16B
    const f4* __restrict__ bp = (const f4*)fm + (size_t)s_base * CH4 + lane;

    f4 acc = (f4){-INFINITY, -INFINITY, -INFINITY, -INFINITY};

    if (s_npix > 0) {
        // magic divide by wbin: q = (p*m)>>16 == p/wbin for p*e < 2^16
        // (computed once per wave from the SGPR wbin)
        const unsigned m = (65536u + (unsigned)s_wbin - 1) / (unsigned)s_wbin;

        for (int p = 0; p < s_npix; p += 8) {
            f4 v[8];
#pragma unroll
            for (int k = 0; k < 8; ++k) {
                const int pk = min(p + k, s_npix - 1);          // clamp: dup ok
                const int q  = (int)(((unsigned)pk * m) >> 16); // row in bin
                const int w  = pk - q * s_wbin;                 // col in bin
                v[k] = bp[(q * WW + w) * CH4];                  // uniform off
            }
#pragma unroll
            for (int k = 0; k < 8; ++k)
                acc = max4(acc, v[k]);
        }
    }

    // Output (b,r,ph,pw,C): gbin = b*6272 + local; non-temporal (never re-read).
    const size_t gbin = (size_t)b * BINS_PER_IMG + local;
    __builtin_nontemporal_store(acc, (f4*)out + gbin * CH4 + lane);
}

extern "C" void kernel_launch(void* const* d_in, const int* in_sizes, int n_in,
                              void* d_out, int out_size, void* d_ws, size_t ws_size,
                              hipStream_t stream) {
    const float* fm   = (const float*)d_in[0];
    const float* rois = (const float*)d_in[1];
    float* out        = (float*)d_out;
    ROIPoolingLayer_62079457296467_kernel<<<NBLK, 256, 0, stream>>>(fm, rois, out);
}